// Round 14
// baseline (190.568 us; speedup 1.0000x reference)
//
#include <hip/hip_runtime.h>

// ---------------------------------------------------------------------------
// Workspace:
//   idxb 0        : (2048,100) int       819200
//   sdn  819200   : (6,3,128)              9216
//   stp  828416   : 6 layers x 32 banks x 256 f32  196608   (BN partials)
//   fo   1025024  : 3 x (2048,256)       6291456
//   p0.. 7316480  : 6 x (2048,128)       6291456
// ---------------------------------------------------------------------------

// ---------------------------------------------------------------------------
// GEMM body (chunked-LDS W): out[r0..r0+7, :256] = bn_relu?(in) @ W + bias.
// 8 rows/block, 256 threads = 2 rows x 4 cols. stp: 32-bank partials.
// ---------------------------------------------------------------------------
__device__ __forceinline__ void do_gemm(
    const float* __restrict__ in, const float* __restrict__ stp,
    const float* __restrict__ gm, const float* __restrict__ bt,
    const float* __restrict__ W, const float* __restrict__ bi,
    float* __restrict__ out, int rb, char* smemc)
{
    float* rows  = (float*)smemc;           // 1024 floats
    float* wch   = rows + 1024;             // 4096 floats (16 KB)
    float* scale = wch + 4096;              // 128
    float* shift = scale + 128;             // 128
    int t = threadIdx.x;
    if (t < 128) {
        float sc = 1.0f, sf = 0.0f;
        if (stp) {
            float sm = 0.0f, sq = 0.0f;
            #pragma unroll 8
            for (int bk = 0; bk < 32; ++bk) {
                sm += stp[bk*256 + t];
                sq += stp[bk*256 + 128 + t];
            }
            float mu  = sm * (1.0f/2048.0f);
            float var = sq * (1.0f/2048.0f) - mu*mu;
            sc = rsqrtf(var + 1e-5f) * gm[t];
            sf = bt[t] - mu*sc;
        }
        scale[t] = sc; shift[t] = sf;
    }
    __syncthreads();
    int r0 = rb * 8;
    {
        float4 v = ((const float4*)(in + r0*128))[t];
        if (stp) {
            int c4 = (t & 31) << 2;
            v.x = fmaxf(v.x*scale[c4  ] + shift[c4  ], 0.0f);
            v.y = fmaxf(v.y*scale[c4+1] + shift[c4+1], 0.0f);
            v.z = fmaxf(v.z*scale[c4+2] + shift[c4+2], 0.0f);
            v.w = fmaxf(v.w*scale[c4+3] + shift[c4+3], 0.0f);
        }
        ((float4*)rows)[t] = v;
    }
    int cb = t & 63, rp = (t >> 6) << 1;
    const float* a0r = rows + rp*128;
    const float* a1r = a0r + 128;
    const float4* W4 = (const float4*)W;
    float4* wch4 = (float4*)wch;
    float4 acc0 = make_float4(0.f,0.f,0.f,0.f);
    float4 acc1 = make_float4(0.f,0.f,0.f,0.f);
    for (int c = 0; c < 8; ++c) {
        __syncthreads();
        #pragma unroll
        for (int i = 0; i < 4; ++i)
            wch4[t + 256*i] = W4[c*1024 + t + 256*i];
        __syncthreads();
        int kb = c*16;
        #pragma unroll
        for (int k = 0; k < 16; k += 4) {
            float4 a0 = *(const float4*)(a0r + kb + k);
            float4 a1 = *(const float4*)(a1r + kb + k);
            float4 w;
            w = wch4[(k+0)*64+cb];
            acc0.x += a0.x*w.x; acc0.y += a0.x*w.y; acc0.z += a0.x*w.z; acc0.w += a0.x*w.w;
            acc1.x += a1.x*w.x; acc1.y += a1.x*w.y; acc1.z += a1.x*w.z; acc1.w += a1.x*w.w;
            w = wch4[(k+1)*64+cb];
            acc0.x += a0.y*w.x; acc0.y += a0.y*w.y; acc0.z += a0.y*w.z; acc0.w += a0.y*w.w;
            acc1.x += a1.y*w.x; acc1.y += a1.y*w.y; acc1.z += a1.y*w.z; acc1.w += a1.y*w.w;
            w = wch4[(k+2)*64+cb];
            acc0.x += a0.z*w.x; acc0.y += a0.z*w.y; acc0.z += a0.z*w.z; acc0.w += a0.z*w.w;
            acc1.x += a1.z*w.x; acc1.y += a1.z*w.y; acc1.z += a1.z*w.z; acc1.w += a1.z*w.w;
            w = wch4[(k+3)*64+cb];
            acc0.x += a0.w*w.x; acc0.y += a0.w*w.y; acc0.z += a0.w*w.z; acc0.w += a0.w*w.w;
            acc1.x += a1.w*w.x; acc1.y += a1.w*w.y; acc1.z += a1.w*w.z; acc1.w += a1.w*w.w;
        }
    }
    float4 b4 = ((const float4*)bi)[cb];
    acc0.x += b4.x; acc0.y += b4.y; acc0.z += b4.z; acc0.w += b4.w;
    acc1.x += b4.x; acc1.y += b4.y; acc1.z += b4.z; acc1.w += b4.w;
    ((float4*)out)[(r0+rp  )*64 + cb] = acc0;
    ((float4*)out)[(r0+rp+1)*64 + cb] = acc1;
}

// ---------------------------------------------------------------------------
// K1: wave-sync knn (0..511) + gemmA (512..1279) + zero stp (1280..1471) +
// dirs norm (1472). knn algorithm verified r8-r13.
// ---------------------------------------------------------------------------
__global__ void k1_kernel(const float* __restrict__ verts, const float* __restrict__ dirs,
                          const float* __restrict__ x,
                          const float* __restrict__ convW, const float* __restrict__ convB,
                          int* __restrict__ idxout, float* __restrict__ sdn,
                          float* __restrict__ stp, float* __restrict__ fo)
{
    __shared__ __align__(16) char smem[21504];
    int t = threadIdx.x;
    int blk = blockIdx.x;

    if (blk >= 1280) {
        if (blk == 1472) {
            for (int i = t; i < 768; i += 256) {
                int l = i >> 7, k = i & 127;
                float a = dirs[l*384 + k];
                float b = dirs[l*384 + 128 + k];
                float c = dirs[l*384 + 256 + k];
                float nrm = sqrtf(a*a + b*b + c*c);
                float inv = 1.0f / fmaxf(nrm, 1e-12f);
                sdn[l*384 + k]       = a*inv;
                sdn[l*384 + 128 + k] = b*inv;
                sdn[l*384 + 256 + k] = c*inv;
            }
        } else {
            stp[(blk - 1280)*256 + t] = 0.0f;
        }
        return;
    }
    if (blk >= 512) {
        int g = blk - 512;
        int s = g >> 8, rb = g & 255;
        int wi = (s==0) ? 0 : (s==1) ? 1 : 3;
        do_gemm(x, (const float*)0, (const float*)0, (const float*)0,
                convW + wi*32768, convB + wi*256, fo + s*524288, rb, smem);
        return;
    }

    // ---------------- knn: one wave per vertex ----------------
    float* xs  = (float*)smem;
    float* ys  = xs + 1024;
    float* zs  = ys + 1024;
    float* sqs = zs + 1024;
    unsigned int* histBase = (unsigned int*)(smem + 16384);
    unsigned int* selBase  = (unsigned int*)(smem + 20480);

    int w = t >> 6, l = t & 63;
    int vglob = blk*4 + w;
    int b = vglob >> 10;
    int v = vglob & 1023;
    unsigned long long* keys = (unsigned long long*)smem + w*256;  // alias xs/ys
    unsigned int* hist = histBase + w*256;
    unsigned int* sel  = selBase + w*4;

    const float* vb = verts + b * 3072;
    for (int i = t; i < 1024; i += 256) {
        float xx = vb[i*3+0], yy = vb[i*3+1], zz = vb[i*3+2];
        xs[i] = xx; ys[i] = yy; zs[i] = zz;
        sqs[i] = xx*xx + yy*yy + zz*zz;
    }
    __syncthreads();

    float cx = xs[v], cy = ys[v], cz = zs[v], csq = sqs[v];
    unsigned long long K16[16];
    #pragma unroll
    for (int q = 0; q < 16; ++q) {
        int j = q*64 + l;
        float dot = cx*xs[j] + cy*ys[j] + cz*zs[j];
        float d = -2.0f*dot + csq + sqs[j];
        unsigned int u = __float_as_uint(d);
        u = (u & 0x80000000u) ? ~u : (u | 0x80000000u);
        K16[q] = (((unsigned long long)u) << 32) | (unsigned long long)j;
    }
    #pragma unroll
    for (int i = 0; i < 4; ++i) hist[l*4 + i] = 0u;
    __syncthreads();

    #pragma unroll
    for (int q = 0; q < 16; ++q)
        atomicAdd(&hist[(unsigned int)(K16[q] >> 56)], 1u);
    __syncthreads();

    {
        unsigned int h0 = hist[l*4], h1 = hist[l*4+1], h2 = hist[l*4+2], h3 = hist[l*4+3];
        unsigned int c1 = h0, c2 = h0+h1, c3 = h0+h1+h2, T = c3+h3;
        unsigned int xacc = T;
        #pragma unroll
        for (int off = 1; off < 64; off <<= 1) {
            unsigned int y = __shfl_up(xacc, off, 64);
            if (l >= off) xacc += y;
        }
        unsigned int P = xacc - T;
        unsigned int ex[4] = {P, P+c1, P+c2, P+c3};
        unsigned int hh[4] = {h0, h1, h2, h3};
        #pragma unroll
        for (int i = 0; i < 4; ++i) {
            if (ex[i] < 101u && ex[i] + hh[i] >= 101u) {
                sel[0] = (unsigned int)(l*4 + i);
                sel[1] = 101u - ex[i];
            }
        }
    }
    __syncthreads();
    unsigned int P8 = sel[0], rank2 = sel[1];
    #pragma unroll
    for (int i = 0; i < 4; ++i) hist[l*4 + i] = 0u;
    __syncthreads();

    #pragma unroll
    for (int q = 0; q < 16; ++q)
        if ((unsigned int)(K16[q] >> 56) == P8)
            atomicAdd(&hist[(unsigned int)(K16[q] >> 48) & 0xFFu], 1u);
    __syncthreads();

    {
        unsigned int h0 = hist[l*4], h1 = hist[l*4+1], h2 = hist[l*4+2], h3 = hist[l*4+3];
        unsigned int c1 = h0, c2 = h0+h1, c3 = h0+h1+h2, T = c3+h3;
        unsigned int xacc = T;
        #pragma unroll
        for (int off = 1; off < 64; off <<= 1) {
            unsigned int y = __shfl_up(xacc, off, 64);
            if (l >= off) xacc += y;
        }
        unsigned int P = xacc - T;
        unsigned int ex[4] = {P, P+c1, P+c2, P+c3};
        unsigned int hh[4] = {h0, h1, h2, h3};
        #pragma unroll
        for (int i = 0; i < 4; ++i) {
            if (ex[i] < rank2 && ex[i] + hh[i] >= rank2) {
                sel[2] = (P8 << 8) | (unsigned int)(l*4 + i);
                sel[3] = 0u;
            }
        }
    }
    __syncthreads();
    unsigned int P16 = sel[2];

    #pragma unroll
    for (int q = 0; q < 16; ++q) {
        if ((unsigned int)(K16[q] >> 48) <= P16) {
            unsigned int pos = atomicAdd(&sel[3], 1u);
            if (pos < 256u) keys[pos] = K16[q];
        }
    }
    __syncthreads();
    unsigned int cnt = sel[3];

    unsigned long long K[4];
    #pragma unroll
    for (int q = 0; q < 4; ++q) {
        unsigned int e = (unsigned int)(l*4 + q);
        K[q] = (e < cnt) ? keys[e] : 0xFFFFFFFFFFFFFFFFULL;
    }

    auto cswap = [&](int qa, int qb, int k) {
        int e = (l << 2) + qa;
        bool up = ((e & k) == 0);
        unsigned long long a = K[qa], bb2 = K[qb];
        unsigned long long mn = a < bb2 ? a : bb2;
        unsigned long long mx = a < bb2 ? bb2 : a;
        K[qa] = up ? mn : mx;
        K[qb] = up ? mx : mn;
    };
    #pragma unroll
    for (int k = 2; k <= 256; k <<= 1) {
        for (int j = k >> 1; j >= 4; j >>= 1) {
            int lj = j >> 2;
            #pragma unroll
            for (int q = 0; q < 4; ++q) {
                unsigned long long other = __shfl_xor(K[q], lj, 64);
                int e = (l << 2) + q;
                bool up = ((e & k) == 0);
                bool lower = ((l & lj) == 0);
                bool takeMin = (lower == up);
                unsigned long long mn = K[q] < other ? K[q] : other;
                unsigned long long mx = K[q] < other ? other : K[q];
                K[q] = takeMin ? mn : mx;
            }
        }
        if (k >= 4) { cswap(0, 2, k); cswap(1, 3, k); }
        cswap(0, 1, k); cswap(2, 3, k);
    }

    #pragma unroll
    for (int q = 0; q < 4; ++q) {
        int e = l*4 + q;
        if (e >= 1 && e <= 100)
            idxout[vglob*100 + (e-1)] = (int)(K[q] & 0xFFFFFFFFu);
    }
}

// ---------------------------------------------------------------------------
// Agg (short-chain): 1 row per 256-thread block. Neighbors split across the
// two half-blocks (h = t>>7): half h handles [h*nh, min(n, (h+1)*nh)),
// batched 10 outstanding gathers per round -> n=100 chain = 5 rounds
// (was 20). Halves combined via LDS max. Fused BN partial atomics (h==0).
// ---------------------------------------------------------------------------
__global__ void agg_kernel(const int* __restrict__ idx, const float* __restrict__ verts,
                           const float* __restrict__ sdn, const float* __restrict__ fo,
                           int n0, int n1, int n2, int d0, int d1, int d2,
                           float* o0, float* o1, float* o2,
                           float* s0p, float* s1p, float* s2p)
{
    __shared__ float4 ds4[100];
    __shared__ int js[100];
    __shared__ float pm[2][128];
    int slot = blockIdx.y;
    int n  = slot==0 ? n0 : slot==1 ? n1 : n2;
    int dI = slot==0 ? d0 : slot==1 ? d1 : d2;
    float* outp = slot==0 ? o0 : slot==1 ? o1 : o2;
    float* stp  = slot==0 ? s0p : slot==1 ? s1p : s2p;
    const float* fos = fo + slot * 524288;
    const float* sd = sdn + dI * 384;

    int t = threadIdx.x;
    int h = t >> 7, tt = t & 127;
    int r = blockIdx.x;
    int b = r >> 10;

    if (t < n) {
        int j = idx[r*100 + t];
        js[t] = j;
        const float* pj = verts + (b*1024 + j)*3;
        const float* pv = verts + r*3;
        float dx = pj[0]-pv[0], dy = pj[1]-pv[1], dz = pj[2]-pv[2];
        float nm = sqrtf(dx*dx + dy*dy + dz*dz);
        float inv = 1.0f / fmaxf(nm, 1e-12f);
        ds4[t] = make_float4(dx*inv, dy*inv, dz*inv, 0.0f);
    }
    __syncthreads();
    float s0 = sd[tt], s1 = sd[128+tt], s2 = sd[256+tt];
    int bb = b * 1024;
    int nh = (n + 1) >> 1;
    int qs = h * nh;
    int qe = min(n, qs + nh);
    float m = -3.0e38f;
    for (int q0 = qs; q0 < qe; q0 += 10) {
        float th[10], vv[10];
        #pragma unroll
        for (int u = 0; u < 10; ++u) {
            int q = q0 + u;
            int qc = (q < qe) ? q : qs;            // safe index for pad lanes
            float4 dq = ds4[qc];
            th[u] = fmaxf(dq.x*s0 + dq.y*s1 + dq.z*s2, 0.0f);
            vv[u] = fos[(size_t)(bb + js[qc])*256 + 128 + tt];
        }
        #pragma unroll
        for (int u = 0; u < 10; ++u) {
            int q = q0 + u;
            float prod = th[u]*vv[u];
            m = fmaxf(m, (q < qe) ? prod : -3.0e38f);
        }
    }
    pm[h][tt] = m;
    __syncthreads();
    if (h == 0) {
        float mm = fmaxf(pm[0][tt], pm[1][tt]);
        float val = fos[r*256 + tt] + mm;
        outp[r*128 + tt] = val;
        float* bank = stp + (r & 31)*256;
        atomicAdd(&bank[tt], val);
        atomicAdd(&bank[128+tt], val*val);
    }
}

// ---------------------------------------------------------------------------
// Standalone gemm, up to 2 slots via blockIdx.y. grid (256, nslots), 256 thr.
// ---------------------------------------------------------------------------
__global__ void gemm2_kernel(
    const float* inA, const float* stA, const float* gA, const float* beA,
    const float* WA, const float* biA, float* foA,
    const float* inB, const float* stB, const float* gB, const float* beB,
    const float* WB, const float* biB, float* foB)
{
    __shared__ __align__(16) char smem[21504];
    if (blockIdx.y == 0)
        do_gemm(inA, stA, gA, beA, WA, biA, foA, blockIdx.x, smem);
    else
        do_gemm(inB, stB, gB, beB, WB, biB, foB, blockIdx.x, smem);
}

// ---------------------------------------------------------------------------
// Down-proj (chunked-LDS W): [bn(p0)|bn(p1)|bn(p2)] (384) @ dW + db, relu.
// 8 rows/block (256 blocks). BN scales from 32-bank partials.
// ---------------------------------------------------------------------------
__global__ void down_kernel(
    const float* __restrict__ p0, const float* __restrict__ s0p,
    const float* __restrict__ g0, const float* __restrict__ be0,
    const float* __restrict__ p1, const float* __restrict__ s1p,
    const float* __restrict__ g1, const float* __restrict__ be1,
    const float* __restrict__ p2, const float* __restrict__ s2p,
    const float* __restrict__ g2, const float* __restrict__ be2,
    const float* __restrict__ dW, const float* __restrict__ db,
    float* __restrict__ out)
{
    __shared__ float rows[8*384];
    __shared__ float wch[16*256];
    __shared__ float scale[384], shift[384];
    int t = threadIdx.x;
    int r0 = blockIdx.x * 8;
    for (int c = t; c < 384; c += 256) {
        int seg = c >> 7, cc = c & 127;
        const float* stp = seg==0 ? s0p : seg==1 ? s1p : s2p;
        const float* g   = seg==0 ? g0  : seg==1 ? g1  : g2;
        const float* be  = seg==0 ? be0 : seg==1 ? be1 : be2;
        float sm = 0.0f, sq = 0.0f;
        #pragma unroll 8
        for (int bk = 0; bk < 32; ++bk) {
            sm += stp[bk*256 + cc];
            sq += stp[bk*256 + 128 + cc];
        }
        float mu  = sm * (1.0f/2048.0f);
        float var = sq * (1.0f/2048.0f) - mu*mu;
        float s = rsqrtf(var + 1e-5f) * g[cc];
        scale[c] = s;
        shift[c] = be[cc] - mu*s;
    }
    __syncthreads();
    for (int q = t; q < 768; q += 256) {
        int row = q / 96, rem = q - row*96;
        int c4 = rem << 2;
        int seg = c4 >> 7, cc = c4 & 127;
        const float* ps = seg==0 ? p0 : seg==1 ? p1 : p2;
        float4 v = *(const float4*)(ps + (r0+row)*128 + cc);
        v.x = fmaxf(v.x*scale[c4  ] + shift[c4  ], 0.0f);
        v.y = fmaxf(v.y*scale[c4+1] + shift[c4+1], 0.0f);
        v.z = fmaxf(v.z*scale[c4+2] + shift[c4+2], 0.0f);
        v.w = fmaxf(v.w*scale[c4+3] + shift[c4+3], 0.0f);
        *(float4*)&rows[row*384 + c4] = v;
    }
    int cb = t & 63, rp = (t >> 6) << 1;
    const float* a0r = rows + rp*384;
    const float* a1r = a0r + 384;
    const float4* W4 = (const float4*)dW;
    float4* wch4 = (float4*)wch;
    float4 acc0 = make_float4(0.f,0.f,0.f,0.f);
    float4 acc1 = make_float4(0.f,0.f,0.f,0.f);
    for (int c = 0; c < 24; ++c) {
        __syncthreads();
        #pragma unroll
        for (int i = 0; i < 4; ++i)
            wch4[t + 256*i] = W4[c*1024 + t + 256*i];
        __syncthreads();
        int kb = c*16;
        #pragma unroll
        for (int k = 0; k < 16; k += 4) {
            float4 a0 = *(const float4*)(a0r + kb + k);
            float4 a1 = *(const float4*)(a1r + kb + k);
            float4 w;
            w = wch4[(k+0)*64+cb];
            acc0.x += a0.x*w.x; acc0.y += a0.x*w.y; acc0.z += a0.x*w.z; acc0.w += a0.x*w.w;
            acc1.x += a1.x*w.x; acc1.y += a1.x*w.y; acc1.z += a1.x*w.z; acc1.w += a1.x*w.w;
            w = wch4[(k+1)*64+cb];
            acc0.x += a0.y*w.x; acc0.y += a0.y*w.y; acc0.z += a0.y*w.z; acc0.w += a0.y*w.w;
            acc1.x += a1.y*w.x; acc1.y += a1.y*w.y; acc1.z += a1.y*w.z; acc1.w += a1.y*w.w;
            w = wch4[(k+2)*64+cb];
            acc0.x += a0.z*w.x; acc0.y += a0.z*w.y; acc0.z += a0.z*w.z; acc0.w += a0.z*w.w;
            acc1.x += a1.z*w.x; acc1.y += a1.z*w.y; acc1.z += a1.z*w.z; acc1.w += a1.z*w.w;
            w = wch4[(k+3)*64+cb];
            acc0.x += a0.w*w.x; acc0.y += a0.w*w.y; acc0.z += a0.w*w.z; acc0.w += a0.w*w.w;
            acc1.x += a1.w*w.x; acc1.y += a1.w*w.y; acc1.z += a1.w*w.z; acc1.w += a1.w*w.w;
        }
    }
    float4 b4 = ((const float4*)db)[cb];
    float4 o0, o1;
    o0.x = fmaxf(acc0.x + b4.x, 0.0f); o0.y = fmaxf(acc0.y + b4.y, 0.0f);
    o0.z = fmaxf(acc0.z + b4.z, 0.0f); o0.w = fmaxf(acc0.w + b4.w, 0.0f);
    o1.x = fmaxf(acc1.x + b4.x, 0.0f); o1.y = fmaxf(acc1.y + b4.y, 0.0f);
    o1.z = fmaxf(acc1.z + b4.z, 0.0f); o1.w = fmaxf(acc1.w + b4.w, 0.0f);
    ((float4*)out)[(r0+rp  )*64 + cb] = o0;
    ((float4*)out)[(r0+rp+1)*64 + cb] = o1;
}

// ---------------------------------------------------------------------------
extern "C" void kernel_launch(void* const* d_in, const int* in_sizes, int n_in,
                              void* d_out, int out_size, void* d_ws, size_t ws_size,
                              hipStream_t stream)
{
    (void)in_sizes; (void)n_in; (void)out_size; (void)ws_size;
    const float* verts = (const float*)d_in[0];
    const float* x     = (const float*)d_in[1];
    const float* convW = (const float*)d_in[2];
    const float* convB = (const float*)d_in[3];
    const float* dirs  = (const float*)d_in[4];
    const float* gam   = (const float*)d_in[5];
    const float* bet   = (const float*)d_in[6];
    const float* dW    = (const float*)d_in[7];
    const float* db    = (const float*)d_in[8];
    float* out = (float*)d_out;

    char* ws = (char*)d_ws;
    int*   idxb = (int*)(ws);
    float* sdn  = (float*)(ws + 819200);
    float* stp  = (float*)(ws + 828416);         // 6 x 32 x 256 f32
    float* fo   = (float*)(ws + 1025024);        // 3 x (2048,256)
    float* p0   = (float*)(ws + 7316480);
    float* p1   = (float*)(ws + 8365056);
    float* p2   = (float*)(ws + 9413632);
    float* p3   = (float*)(ws + 10462208);
    float* p4   = (float*)(ws + 11510784);
    float* p5   = (float*)(ws + 12559360);

    const float* nf = (const float*)0;
    float* nw = (float*)0;
    float* stL0 = stp,         *stL1 = stp + 8192, *stL2 = stp + 16384;
    float* stL3 = stp + 24576, *stL4 = stp + 32768, *stL5 = stp + 40960;

    // K1: knn + gemmA (L0,L1,L3 from x) + zero stp + dirs norm
    k1_kernel<<<1473, 256, 0, stream>>>(verts, dirs, x, convW, convB,
                                        idxb, sdn, stp, fo);
    // K2: aggA -> p0 (n5,d0,stL0), p1 (n20,d1,stL1), p3 (n100,d3,stL3)
    agg_kernel<<<dim3(2048,3), 256, 0, stream>>>(
        idxb, verts, sdn, fo, 5, 20, 100, 0, 1, 3,
        p0, p1, p3, stL0, stL1, stL3);
    // K3: gemmB: L2 from bn(p1,stL1,g1,b1); L4 from bn(p3,stL3,g3,b3)
    gemm2_kernel<<<dim3(256,2), 256, 0, stream>>>(
        p1, stL1, gam + 128, bet + 128, convW + 65536,  convB + 512,  fo,
        p3, stL3, gam + 384, bet + 384, convW + 131072, convB + 1024, fo + 524288);
    // K4: aggB -> p2 (n20,d2,stL2), p4 (n100,d4,stL4)
    agg_kernel<<<dim3(2048,2), 256, 0, stream>>>(
        idxb, verts, sdn, fo, 20, 100, 0, 2, 4, 0,
        p2, p4, nw, stL2, stL4, nw);
    // K5: gemmC: L5-conv (params3) from bn(p4,stL4,g4,b4)
    gemm2_kernel<<<dim3(256,1), 256, 0, stream>>>(
        p4, stL4, gam + 512, bet + 512, convW + 98304, convB + 768, fo,
        nf, nf, nf, nf, nf, nf, nw);
    // K6: aggC -> p5 (n100,d3,stL5)
    agg_kernel<<<dim3(2048,1), 256, 0, stream>>>(
        idxb, verts, sdn, fo, 100, 0, 0, 3, 0, 0,
        p5, nw, nw, stL5, nw, nw);
    // K7: down: bn(p0,stL0,g0,b0) | bn(p2,stL2,g2,b2) | bn(p5,stL5,g3,b3)
    down_kernel<<<256, 256, 0, stream>>>(
        p0, stL0, gam, bet,
        p2, stL2, gam + 256, bet + 256,
        p5, stL5, gam + 384, bet + 384,
        dW, db, out);
}

// Round 15
// 190.309 us; speedup vs baseline: 1.0014x; 1.0014x over previous
//
#include <hip/hip_runtime.h>

// ---------------------------------------------------------------------------
// Round-13 structure (best measured: 187.8us). 7 stages, irreducibly serial
// (BN global stats force a device-wide barrier per layer; cooperative
// grid.sync measured ~60us/barrier on gfx950 -> stream dispatch is cheaper).
// Workspace:
//   idxb 0        : (2048,100) int       819200
//   sdn  819200   : (6,3,128)              9216
//   stp  828416   : 6 layers x 32 banks x 256 f32  196608   (BN partials)
//   fo   1025024  : 3 x (2048,256)       6291456
//   p0.. 7316480  : 6 x (2048,128)       6291456
// ---------------------------------------------------------------------------

__device__ __forceinline__ void do_gemm(
    const float* __restrict__ in, const float* __restrict__ stp,
    const float* __restrict__ gm, const float* __restrict__ bt,
    const float* __restrict__ W, const float* __restrict__ bi,
    float* __restrict__ out, int rb, char* smemc)
{
    float* rows  = (float*)smemc;           // 1024 floats
    float* wch   = rows + 1024;             // 4096 floats (16 KB)
    float* scale = wch + 4096;              // 128
    float* shift = scale + 128;             // 128
    int t = threadIdx.x;
    if (t < 128) {
        float sc = 1.0f, sf = 0.0f;
        if (stp) {
            float sm = 0.0f, sq = 0.0f;
            #pragma unroll 8
            for (int bk = 0; bk < 32; ++bk) {
                sm += stp[bk*256 + t];
                sq += stp[bk*256 + 128 + t];
            }
            float mu  = sm * (1.0f/2048.0f);
            float var = sq * (1.0f/2048.0f) - mu*mu;
            sc = rsqrtf(var + 1e-5f) * gm[t];
            sf = bt[t] - mu*sc;
        }
        scale[t] = sc; shift[t] = sf;
    }
    __syncthreads();
    int r0 = rb * 8;
    {
        float4 v = ((const float4*)(in + r0*128))[t];
        if (stp) {
            int c4 = (t & 31) << 2;
            v.x = fmaxf(v.x*scale[c4  ] + shift[c4  ], 0.0f);
            v.y = fmaxf(v.y*scale[c4+1] + shift[c4+1], 0.0f);
            v.z = fmaxf(v.z*scale[c4+2] + shift[c4+2], 0.0f);
            v.w = fmaxf(v.w*scale[c4+3] + shift[c4+3], 0.0f);
        }
        ((float4*)rows)[t] = v;
    }
    int cb = t & 63, rp = (t >> 6) << 1;
    const float* a0r = rows + rp*128;
    const float* a1r = a0r + 128;
    const float4* W4 = (const float4*)W;
    float4* wch4 = (float4*)wch;
    float4 acc0 = make_float4(0.f,0.f,0.f,0.f);
    float4 acc1 = make_float4(0.f,0.f,0.f,0.f);
    for (int c = 0; c < 8; ++c) {
        __syncthreads();
        #pragma unroll
        for (int i = 0; i < 4; ++i)
            wch4[t + 256*i] = W4[c*1024 + t + 256*i];
        __syncthreads();
        int kb = c*16;
        #pragma unroll
        for (int k = 0; k < 16; k += 4) {
            float4 a0 = *(const float4*)(a0r + kb + k);
            float4 a1 = *(const float4*)(a1r + kb + k);
            float4 w;
            w = wch4[(k+0)*64+cb];
            acc0.x += a0.x*w.x; acc0.y += a0.x*w.y; acc0.z += a0.x*w.z; acc0.w += a0.x*w.w;
            acc1.x += a1.x*w.x; acc1.y += a1.x*w.y; acc1.z += a1.x*w.z; acc1.w += a1.x*w.w;
            w = wch4[(k+1)*64+cb];
            acc0.x += a0.y*w.x; acc0.y += a0.y*w.y; acc0.z += a0.y*w.z; acc0.w += a0.y*w.w;
            acc1.x += a1.y*w.x; acc1.y += a1.y*w.y; acc1.z += a1.y*w.z; acc1.w += a1.y*w.w;
            w = wch4[(k+2)*64+cb];
            acc0.x += a0.z*w.x; acc0.y += a0.z*w.y; acc0.z += a0.z*w.z; acc0.w += a0.z*w.w;
            acc1.x += a1.z*w.x; acc1.y += a1.z*w.y; acc1.z += a1.z*w.z; acc1.w += a1.z*w.w;
            w = wch4[(k+3)*64+cb];
            acc0.x += a0.w*w.x; acc0.y += a0.w*w.y; acc0.z += a0.w*w.z; acc0.w += a0.w*w.w;
            acc1.x += a1.w*w.x; acc1.y += a1.w*w.y; acc1.z += a1.w*w.z; acc1.w += a1.w*w.w;
        }
    }
    float4 b4 = ((const float4*)bi)[cb];
    acc0.x += b4.x; acc0.y += b4.y; acc0.z += b4.z; acc0.w += b4.w;
    acc1.x += b4.x; acc1.y += b4.y; acc1.z += b4.z; acc1.w += b4.w;
    ((float4*)out)[(r0+rp  )*64 + cb] = acc0;
    ((float4*)out)[(r0+rp+1)*64 + cb] = acc1;
}

// ---------------------------------------------------------------------------
// K1: wave-sync knn (0..511) + gemmA (512..1279) + zero stp (1280..1471) +
// dirs norm (1472). knn algorithm verified r8-r14.
// ---------------------------------------------------------------------------
__global__ void k1_kernel(const float* __restrict__ verts, const float* __restrict__ dirs,
                          const float* __restrict__ x,
                          const float* __restrict__ convW, const float* __restrict__ convB,
                          int* __restrict__ idxout, float* __restrict__ sdn,
                          float* __restrict__ stp, float* __restrict__ fo)
{
    __shared__ __align__(16) char smem[21504];
    int t = threadIdx.x;
    int blk = blockIdx.x;

    if (blk >= 1280) {
        if (blk == 1472) {
            for (int i = t; i < 768; i += 256) {
                int l = i >> 7, k = i & 127;
                float a = dirs[l*384 + k];
                float b = dirs[l*384 + 128 + k];
                float c = dirs[l*384 + 256 + k];
                float nrm = sqrtf(a*a + b*b + c*c);
                float inv = 1.0f / fmaxf(nrm, 1e-12f);
                sdn[l*384 + k]       = a*inv;
                sdn[l*384 + 128 + k] = b*inv;
                sdn[l*384 + 256 + k] = c*inv;
            }
        } else {
            stp[(blk - 1280)*256 + t] = 0.0f;
        }
        return;
    }
    if (blk >= 512) {
        int g = blk - 512;
        int s = g >> 8, rb = g & 255;
        int wi = (s==0) ? 0 : (s==1) ? 1 : 3;
        do_gemm(x, (const float*)0, (const float*)0, (const float*)0,
                convW + wi*32768, convB + wi*256, fo + s*524288, rb, smem);
        return;
    }

    // ---------------- knn: one wave per vertex ----------------
    float* xs  = (float*)smem;
    float* ys  = xs + 1024;
    float* zs  = ys + 1024;
    float* sqs = zs + 1024;
    unsigned int* histBase = (unsigned int*)(smem + 16384);
    unsigned int* selBase  = (unsigned int*)(smem + 20480);

    int w = t >> 6, l = t & 63;
    int vglob = blk*4 + w;
    int b = vglob >> 10;
    int v = vglob & 1023;
    unsigned long long* keys = (unsigned long long*)smem + w*256;  // alias xs/ys
    unsigned int* hist = histBase + w*256;
    unsigned int* sel  = selBase + w*4;

    const float* vb = verts + b * 3072;
    for (int i = t; i < 1024; i += 256) {
        float xx = vb[i*3+0], yy = vb[i*3+1], zz = vb[i*3+2];
        xs[i] = xx; ys[i] = yy; zs[i] = zz;
        sqs[i] = xx*xx + yy*yy + zz*zz;
    }
    __syncthreads();

    float cx = xs[v], cy = ys[v], cz = zs[v], csq = sqs[v];
    unsigned long long K16[16];
    #pragma unroll
    for (int q = 0; q < 16; ++q) {
        int j = q*64 + l;
        float dot = cx*xs[j] + cy*ys[j] + cz*zs[j];
        float d = -2.0f*dot + csq + sqs[j];
        unsigned int u = __float_as_uint(d);
        u = (u & 0x80000000u) ? ~u : (u | 0x80000000u);
        K16[q] = (((unsigned long long)u) << 32) | (unsigned long long)j;
    }
    #pragma unroll
    for (int i = 0; i < 4; ++i) hist[l*4 + i] = 0u;
    __syncthreads();

    #pragma unroll
    for (int q = 0; q < 16; ++q)
        atomicAdd(&hist[(unsigned int)(K16[q] >> 56)], 1u);
    __syncthreads();

    {
        unsigned int h0 = hist[l*4], h1 = hist[l*4+1], h2 = hist[l*4+2], h3 = hist[l*4+3];
        unsigned int c1 = h0, c2 = h0+h1, c3 = h0+h1+h2, T = c3+h3;
        unsigned int xacc = T;
        #pragma unroll
        for (int off = 1; off < 64; off <<= 1) {
            unsigned int y = __shfl_up(xacc, off, 64);
            if (l >= off) xacc += y;
        }
        unsigned int P = xacc - T;
        unsigned int ex[4] = {P, P+c1, P+c2, P+c3};
        unsigned int hh[4] = {h0, h1, h2, h3};
        #pragma unroll
        for (int i = 0; i < 4; ++i) {
            if (ex[i] < 101u && ex[i] + hh[i] >= 101u) {
                sel[0] = (unsigned int)(l*4 + i);
                sel[1] = 101u - ex[i];
            }
        }
    }
    __syncthreads();
    unsigned int P8 = sel[0], rank2 = sel[1];
    #pragma unroll
    for (int i = 0; i < 4; ++i) hist[l*4 + i] = 0u;
    __syncthreads();

    #pragma unroll
    for (int q = 0; q < 16; ++q)
        if ((unsigned int)(K16[q] >> 56) == P8)
            atomicAdd(&hist[(unsigned int)(K16[q] >> 48) & 0xFFu], 1u);
    __syncthreads();

    {
        unsigned int h0 = hist[l*4], h1 = hist[l*4+1], h2 = hist[l*4+2], h3 = hist[l*4+3];
        unsigned int c1 = h0, c2 = h0+h1, c3 = h0+h1+h2, T = c3+h3;
        unsigned int xacc = T;
        #pragma unroll
        for (int off = 1; off < 64; off <<= 1) {
            unsigned int y = __shfl_up(xacc, off, 64);
            if (l >= off) xacc += y;
        }
        unsigned int P = xacc - T;
        unsigned int ex[4] = {P, P+c1, P+c2, P+c3};
        unsigned int hh[4] = {h0, h1, h2, h3};
        #pragma unroll
        for (int i = 0; i < 4; ++i) {
            if (ex[i] < rank2 && ex[i] + hh[i] >= rank2) {
                sel[2] = (P8 << 8) | (unsigned int)(l*4 + i);
                sel[3] = 0u;
            }
        }
    }
    __syncthreads();
    unsigned int P16 = sel[2];

    #pragma unroll
    for (int q = 0; q < 16; ++q) {
        if ((unsigned int)(K16[q] >> 48) <= P16) {
            unsigned int pos = atomicAdd(&sel[3], 1u);
            if (pos < 256u) keys[pos] = K16[q];
        }
    }
    __syncthreads();
    unsigned int cnt = sel[3];

    unsigned long long K[4];
    #pragma unroll
    for (int q = 0; q < 4; ++q) {
        unsigned int e = (unsigned int)(l*4 + q);
        K[q] = (e < cnt) ? keys[e] : 0xFFFFFFFFFFFFFFFFULL;
    }

    auto cswap = [&](int qa, int qb, int k) {
        int e = (l << 2) + qa;
        bool up = ((e & k) == 0);
        unsigned long long a = K[qa], bb2 = K[qb];
        unsigned long long mn = a < bb2 ? a : bb2;
        unsigned long long mx = a < bb2 ? bb2 : a;
        K[qa] = up ? mn : mx;
        K[qb] = up ? mx : mn;
    };
    #pragma unroll
    for (int k = 2; k <= 256; k <<= 1) {
        for (int j = k >> 1; j >= 4; j >>= 1) {
            int lj = j >> 2;
            #pragma unroll
            for (int q = 0; q < 4; ++q) {
                unsigned long long other = __shfl_xor(K[q], lj, 64);
                int e = (l << 2) + q;
                bool up = ((e & k) == 0);
                bool lower = ((l & lj) == 0);
                bool takeMin = (lower == up);
                unsigned long long mn = K[q] < other ? K[q] : other;
                unsigned long long mx = K[q] < other ? other : K[q];
                K[q] = takeMin ? mn : mx;
            }
        }
        if (k >= 4) { cswap(0, 2, k); cswap(1, 3, k); }
        cswap(0, 1, k); cswap(2, 3, k);
    }

    #pragma unroll
    for (int q = 0; q < 4; ++q) {
        int e = l*4 + q;
        if (e >= 1 && e <= 100)
            idxout[vglob*100 + (e-1)] = (int)(K[q] & 0xFFFFFFFFu);
    }
}

// ---------------------------------------------------------------------------
// Agg + fused BN-partials (r13 form, 2 rows/block): center value prefetched
// before the neighbor chain; unroll-5 batched gathers.
// ---------------------------------------------------------------------------
__global__ void agg_kernel(const int* __restrict__ idx, const float* __restrict__ verts,
                           const float* __restrict__ sdn, const float* __restrict__ fo,
                           int n0, int n1, int n2, int d0, int d1, int d2,
                           float* o0, float* o1, float* o2,
                           float* s0p, float* s1p, float* s2p)
{
    __shared__ float4 ds4s[200];
    __shared__ int jss[200];
    int slot = blockIdx.y;
    int n  = slot==0 ? n0 : slot==1 ? n1 : n2;
    int dI = slot==0 ? d0 : slot==1 ? d1 : d2;
    float* outp = slot==0 ? o0 : slot==1 ? o1 : o2;
    float* stp  = slot==0 ? s0p : slot==1 ? s1p : s2p;
    const float* fos = fo + slot * 524288;
    const float* sd = sdn + dI * 384;

    int t = threadIdx.x;
    int h = t >> 7, tt = t & 127;
    float4* ds4 = ds4s + h*100;
    int* js = jss + h*100;
    int r = blockIdx.x*2 + h;
    int b = r >> 10;

    if (tt < n) {
        int j = idx[r*100 + tt];
        js[tt] = j;
        const float* pj = verts + (b*1024 + j)*3;
        const float* pv = verts + r*3;
        float dx = pj[0]-pv[0], dy = pj[1]-pv[1], dz = pj[2]-pv[2];
        float nm = sqrtf(dx*dx + dy*dy + dz*dz);
        float inv = 1.0f / fmaxf(nm, 1e-12f);
        ds4[tt] = make_float4(dx*inv, dy*inv, dz*inv, 0.0f);
    }
    float center = fos[r*256 + tt];        // prefetch: in flight across barrier
    __syncthreads();
    float s0 = sd[tt], s1 = sd[128+tt], s2 = sd[256+tt];
    int bb = b * 1024;
    float m = -3.0e38f;
    for (int q = 0; q < n; q += 5) {
        float th[5];
        const float* p[5];
        #pragma unroll
        for (int u = 0; u < 5; ++u) {
            float4 dq = ds4[q+u];
            th[u] = fmaxf(dq.x*s0 + dq.y*s1 + dq.z*s2, 0.0f);
            p[u] = fos + (size_t)(bb + js[q+u])*256 + 128 + tt;
        }
        float vv[5];
        #pragma unroll
        for (int u = 0; u < 5; ++u) vv[u] = *p[u];
        #pragma unroll
        for (int u = 0; u < 5; ++u) m = fmaxf(m, th[u]*vv[u]);
    }
    float val = center + m;
    outp[r*128 + tt] = val;
    float* bank = stp + (r & 31)*256;
    atomicAdd(&bank[tt], val);
    atomicAdd(&bank[128+tt], val*val);
}

// ---------------------------------------------------------------------------
__global__ void gemm2_kernel(
    const float* inA, const float* stA, const float* gA, const float* beA,
    const float* WA, const float* biA, float* foA,
    const float* inB, const float* stB, const float* gB, const float* beB,
    const float* WB, const float* biB, float* foB)
{
    __shared__ __align__(16) char smem[21504];
    if (blockIdx.y == 0)
        do_gemm(inA, stA, gA, beA, WA, biA, foA, blockIdx.x, smem);
    else
        do_gemm(inB, stB, gB, beB, WB, biB, foB, blockIdx.x, smem);
}

// ---------------------------------------------------------------------------
// Down-proj (chunked-LDS W): [bn(p0)|bn(p1)|bn(p2)] (384) @ dW + db, relu.
// 8 rows/block (256 blocks). BN scales from 32-bank partials.
// ---------------------------------------------------------------------------
__global__ void down_kernel(
    const float* __restrict__ p0, const float* __restrict__ s0p,
    const float* __restrict__ g0, const float* __restrict__ be0,
    const float* __restrict__ p1, const float* __restrict__ s1p,
    const float* __restrict__ g1, const float* __restrict__ be1,
    const float* __restrict__ p2, const float* __restrict__ s2p,
    const float* __restrict__ g2, const float* __restrict__ be2,
    const float* __restrict__ dW, const float* __restrict__ db,
    float* __restrict__ out)
{
    __shared__ float rows[8*384];
    __shared__ float wch[16*256];
    __shared__ float scale[384], shift[384];
    int t = threadIdx.x;
    int r0 = blockIdx.x * 8;
    for (int c = t; c < 384; c += 256) {
        int seg = c >> 7, cc = c & 127;
        const float* stp = seg==0 ? s0p : seg==1 ? s1p : s2p;
        const float* g   = seg==0 ? g0  : seg==1 ? g1  : g2;
        const float* be  = seg==0 ? be0 : seg==1 ? be1 : be2;
        float sm = 0.0f, sq = 0.0f;
        #pragma unroll 8
        for (int bk = 0; bk < 32; ++bk) {
            sm += stp[bk*256 + cc];
            sq += stp[bk*256 + 128 + cc];
        }
        float mu  = sm * (1.0f/2048.0f);
        float var = sq * (1.0f/2048.0f) - mu*mu;
        float s = rsqrtf(var + 1e-5f) * g[cc];
        scale[c] = s;
        shift[c] = be[cc] - mu*s;
    }
    __syncthreads();
    for (int q = t; q < 768; q += 256) {
        int row = q / 96, rem = q - row*96;
        int c4 = rem << 2;
        int seg = c4 >> 7, cc = c4 & 127;
        const float* ps = seg==0 ? p0 : seg==1 ? p1 : p2;
        float4 v = *(const float4*)(ps + (r0+row)*128 + cc);
        v.x = fmaxf(v.x*scale[c4  ] + shift[c4  ], 0.0f);
        v.y = fmaxf(v.y*scale[c4+1] + shift[c4+1], 0.0f);
        v.z = fmaxf(v.z*scale[c4+2] + shift[c4+2], 0.0f);
        v.w = fmaxf(v.w*scale[c4+3] + shift[c4+3], 0.0f);
        *(float4*)&rows[row*384 + c4] = v;
    }
    int cb = t & 63, rp = (t >> 6) << 1;
    const float* a0r = rows + rp*384;
    const float* a1r = a0r + 384;
    const float4* W4 = (const float4*)dW;
    float4* wch4 = (float4*)wch;
    float4 acc0 = make_float4(0.f,0.f,0.f,0.f);
    float4 acc1 = make_float4(0.f,0.f,0.f,0.f);
    for (int c = 0; c < 24; ++c) {
        __syncthreads();
        #pragma unroll
        for (int i = 0; i < 4; ++i)
            wch4[t + 256*i] = W4[c*1024 + t + 256*i];
        __syncthreads();
        int kb = c*16;
        #pragma unroll
        for (int k = 0; k < 16; k += 4) {
            float4 a0 = *(const float4*)(a0r + kb + k);
            float4 a1 = *(const float4*)(a1r + kb + k);
            float4 w;
            w = wch4[(k+0)*64+cb];
            acc0.x += a0.x*w.x; acc0.y += a0.x*w.y; acc0.z += a0.x*w.z; acc0.w += a0.x*w.w;
            acc1.x += a1.x*w.x; acc1.y += a1.x*w.y; acc1.z += a1.x*w.z; acc1.w += a1.x*w.w;
            w = wch4[(k+1)*64+cb];
            acc0.x += a0.y*w.x; acc0.y += a0.y*w.y; acc0.z += a0.y*w.z; acc0.w += a0.y*w.w;
            acc1.x += a1.y*w.x; acc1.y += a1.y*w.y; acc1.z += a1.y*w.z; acc1.w += a1.y*w.w;
            w = wch4[(k+2)*64+cb];
            acc0.x += a0.z*w.x; acc0.y += a0.z*w.y; acc0.z += a0.z*w.z; acc0.w += a0.z*w.w;
            acc1.x += a1.z*w.x; acc1.y += a1.z*w.y; acc1.z += a1.z*w.z; acc1.w += a1.z*w.w;
            w = wch4[(k+3)*64+cb];
            acc0.x += a0.w*w.x; acc0.y += a0.w*w.y; acc0.z += a0.w*w.z; acc0.w += a0.w*w.w;
            acc1.x += a1.w*w.x; acc1.y += a1.w*w.y; acc1.z += a1.w*w.z; acc1.w += a1.w*w.w;
        }
    }
    float4 b4 = ((const float4*)db)[cb];
    float4 o0, o1;
    o0.x = fmaxf(acc0.x + b4.x, 0.0f); o0.y = fmaxf(acc0.y + b4.y, 0.0f);
    o0.z = fmaxf(acc0.z + b4.z, 0.0f); o0.w = fmaxf(acc0.w + b4.w, 0.0f);
    o1.x = fmaxf(acc1.x + b4.x, 0.0f); o1.y = fmaxf(acc1.y + b4.y, 0.0f);
    o1.z = fmaxf(acc1.z + b4.z, 0.0f); o1.w = fmaxf(acc1.w + b4.w, 0.0f);
    ((float4*)out)[(r0+rp  )*64 + cb] = o0;
    ((float4*)out)[(r0+rp+1)*64 + cb] = o1;
}

// ---------------------------------------------------------------------------
extern "C" void kernel_launch(void* const* d_in, const int* in_sizes, int n_in,
                              void* d_out, int out_size, void* d_ws, size_t ws_size,
                              hipStream_t stream)
{
    (void)in_sizes; (void)n_in; (void)out_size; (void)ws_size;
    const float* verts = (const float*)d_in[0];
    const float* x     = (const float*)d_in[1];
    const float* convW = (const float*)d_in[2];
    const float* convB = (const float*)d_in[3];
    const float* dirs  = (const float*)d_in[4];
    const float* gam   = (const float*)d_in[5];
    const float* bet   = (const float*)d_in[6];
    const float* dW    = (const float*)d_in[7];
    const float* db    = (const float*)d_in[8];
    float* out = (float*)d_out;

    char* ws = (char*)d_ws;
    int*   idxb = (int*)(ws);
    float* sdn  = (float*)(ws + 819200);
    float* stp  = (float*)(ws + 828416);
    float* fo   = (float*)(ws + 1025024);
    float* p0   = (float*)(ws + 7316480);
    float* p1   = (float*)(ws + 8365056);
    float* p2   = (float*)(ws + 9413632);
    float* p3   = (float*)(ws + 10462208);
    float* p4   = (float*)(ws + 11510784);
    float* p5   = (float*)(ws + 12559360);

    const float* nf = (const float*)0;
    float* nw = (float*)0;
    float* stL0 = stp,         *stL1 = stp + 8192, *stL2 = stp + 16384;
    float* stL3 = stp + 24576, *stL4 = stp + 32768, *stL5 = stp + 40960;

    // K1: knn + gemmA (L0,L1,L3 from x) + zero stp + dirs norm
    k1_kernel<<<1473, 256, 0, stream>>>(verts, dirs, x, convW, convB,
                                        idxb, sdn, stp, fo);
    // K2: aggA -> p0 (n5,d0,stL0), p1 (n20,d1,stL1), p3 (n100,d3,stL3)
    agg_kernel<<<dim3(1024,3), 256, 0, stream>>>(
        idxb, verts, sdn, fo, 5, 20, 100, 0, 1, 3,
        p0, p1, p3, stL0, stL1, stL3);
    // K3: gemmB: L2 from bn(p1,stL1,g1,b1); L4 from bn(p3,stL3,g3,b3)
    gemm2_kernel<<<dim3(256,2), 256, 0, stream>>>(
        p1, stL1, gam + 128, bet + 128, convW + 65536,  convB + 512,  fo,
        p3, stL3, gam + 384, bet + 384, convW + 131072, convB + 1024, fo + 524288);
    // K4: aggB -> p2 (n20,d2,stL2), p4 (n100,d4,stL4)
    agg_kernel<<<dim3(1024,2), 256, 0, stream>>>(
        idxb, verts, sdn, fo, 20, 100, 0, 2, 4, 0,
        p2, p4, nw, stL2, stL4, nw);
    // K5: gemmC: L5-conv (params3) from bn(p4,stL4,g4,b4)
    gemm2_kernel<<<dim3(256,1), 256, 0, stream>>>(
        p4, stL4, gam + 512, bet + 512, convW + 98304, convB + 768, fo,
        nf, nf, nf, nf, nf, nf, nw);
    // K6: aggC -> p5 (n100,d3,stL5)
    agg_kernel<<<dim3(1024,1), 256, 0, stream>>>(
        idxb, verts, sdn, fo, 100, 0, 0, 3, 0, 0,
        p5, nw, nw, stL5, nw, nw);
    // K7: down: bn(p0,stL0,g0,b0) | bn(p2,stL2,g2,b2) | bn(p5,stL5,g3,b3)
    down_kernel<<<256, 256, 0, stream>>>(
        p0, stL0, gam, bet,
        p2, stL2, gam + 256, bet + 256,
        p5, stL5, gam + 384, bet + 384,
        dW, db, out);
}